// Round 1
// baseline (330.794 us; speedup 1.0000x reference)
//
#include <hip/hip_runtime.h>

#define N_NODES 100000
#define N_EDGES 1600000
#define D_FEAT 32

// ws layout (floats):
//   deg : [0, N_NODES)
//   dinv: [N_NODES, 2*N_NODES)
//   agg : [2*N_NODES, 2*N_NODES + N_NODES*D_FEAT)

__global__ void deg_kernel(const int* __restrict__ edge_dst,
                           float* __restrict__ deg, int n_edges) {
    int i = blockIdx.x * blockDim.x + threadIdx.x;
    if (i < n_edges) {
        unsafeAtomicAdd(&deg[edge_dst[i]], 1.0f);
    }
}

__global__ void dinv_kernel(const float* __restrict__ deg,
                            float* __restrict__ dinv, int n_nodes) {
    int i = blockIdx.x * blockDim.x + threadIdx.x;
    if (i < n_nodes) {
        float d = deg[i];
        d = fmaxf(d, 1.0f);
        dinv[i] = rsqrtf(d);
    }
}

// one thread per (edge, feature): gid = e*32 + f
__global__ void scatter_kernel(const float* __restrict__ feat,
                               const int* __restrict__ edge_src,
                               const int* __restrict__ edge_dst,
                               const float* __restrict__ dinv,
                               float* __restrict__ agg, int n_edges) {
    int gid = blockIdx.x * blockDim.x + threadIdx.x;
    int e = gid >> 5;
    int f = gid & 31;
    if (e < n_edges) {
        int s = edge_src[e];
        int d = edge_dst[e];
        float v = feat[s * D_FEAT + f] * dinv[s];
        unsafeAtomicAdd(&agg[d * D_FEAT + f], v);
    }
}

// one thread per float4 of (node, feature): n_nodes * 8 float4s
__global__ void epilogue_kernel(const float* __restrict__ feat,
                                const float* __restrict__ agg,
                                const float* __restrict__ dinv,
                                float* __restrict__ out, int n_nodes) {
    int gid = blockIdx.x * blockDim.x + threadIdx.x;
    int total = n_nodes * (D_FEAT / 4);
    if (gid < total) {
        int node = gid >> 3;  // 8 float4 per node
        float dv = dinv[node];
        float4 fv = reinterpret_cast<const float4*>(feat)[gid];
        float4 av = reinterpret_cast<const float4*>(agg)[gid];
        float4 o;
        float yx = 0.5f * (fv.x - av.x * dv);
        float yy = 0.5f * (fv.y - av.y * dv);
        float yz = 0.5f * (fv.z - av.z * dv);
        float yw = 0.5f * (fv.w - av.w * dv);
        o.x = 2.0f * yx * (fv.x - yx);
        o.y = 2.0f * yy * (fv.y - yy);
        o.z = 2.0f * yz * (fv.z - yz);
        o.w = 2.0f * yw * (fv.w - yw);
        reinterpret_cast<float4*>(out)[gid] = o;
    }
}

extern "C" void kernel_launch(void* const* d_in, const int* in_sizes, int n_in,
                              void* d_out, int out_size, void* d_ws, size_t ws_size,
                              hipStream_t stream) {
    const float* feat = (const float*)d_in[0];
    const int* edge_src = (const int*)d_in[1];
    const int* edge_dst = (const int*)d_in[2];
    float* out = (float*)d_out;

    float* ws = (float*)d_ws;
    float* deg  = ws;
    float* dinv = ws + N_NODES;
    float* agg  = ws + 2 * N_NODES;

    // zero deg + agg (dinv is fully overwritten, harmless to zero too)
    size_t zero_bytes = (size_t)(2 * N_NODES + N_NODES * D_FEAT) * sizeof(float);
    hipMemsetAsync(d_ws, 0, zero_bytes, stream);

    {
        int threads = 256;
        int blocks = (N_EDGES + threads - 1) / threads;
        deg_kernel<<<blocks, threads, 0, stream>>>(edge_dst, deg, N_EDGES);
    }
    {
        int threads = 256;
        int blocks = (N_NODES + threads - 1) / threads;
        dinv_kernel<<<blocks, threads, 0, stream>>>(deg, dinv, N_NODES);
    }
    {
        int threads = 256;
        long long total = (long long)N_EDGES * D_FEAT;
        int blocks = (int)((total + threads - 1) / threads);
        scatter_kernel<<<blocks, threads, 0, stream>>>(feat, edge_src, edge_dst,
                                                       dinv, agg, N_EDGES);
    }
    {
        int threads = 256;
        int total = N_NODES * (D_FEAT / 4);
        int blocks = (total + threads - 1) / threads;
        epilogue_kernel<<<blocks, threads, 0, stream>>>(feat, agg, dinv, out, N_NODES);
    }
}

// Round 2
// 314.540 us; speedup vs baseline: 1.0517x; 1.0517x over previous
//
#include <hip/hip_runtime.h>

#define N_NODES 100000
#define N_EDGES 1600000
#define D_FEAT 32
#define SCAN_BS 1024
#define NSCAN_BLOCKS ((N_NODES + SCAN_BS - 1) / SCAN_BS)   // 98
#define PART_BS 128                                        // >= NSCAN_BLOCKS

// ws layout (4-byte words):
//   cnt    [N_NODES]        int   degree counts
//   row    [N_NODES+1]      int   CSR offsets
//   cursor [N_NODES]        int   fill cursors
//   bsum   [PART_BS]        int   per-scan-block sums
//   boff   [PART_BS]        int   scanned block offsets
//   dinv   [N_NODES]        float
//   ssrc   [N_EDGES]        int   edge srcs sorted by dst

__global__ void count_kernel(const int* __restrict__ edge_dst,
                             int* __restrict__ cnt, int n_edges) {
    int i = blockIdx.x * blockDim.x + threadIdx.x;
    if (i < n_edges) atomicAdd(&cnt[edge_dst[i]], 1);
}

__global__ void reduce_kernel(const int* __restrict__ cnt,
                              int* __restrict__ bsum, int n) {
    __shared__ int s[SCAN_BS];
    int t = threadIdx.x;
    int i = blockIdx.x * SCAN_BS + t;
    s[t] = (i < n) ? cnt[i] : 0;
    __syncthreads();
    for (int off = SCAN_BS / 2; off > 0; off >>= 1) {
        if (t < off) s[t] += s[t + off];
        __syncthreads();
    }
    if (t == 0) bsum[blockIdx.x] = s[0];
}

__global__ void partials_kernel(const int* __restrict__ bsum,
                                int* __restrict__ boff,
                                int* __restrict__ row) {
    __shared__ int s[PART_BS];
    int t = threadIdx.x;
    int val = (t < NSCAN_BLOCKS) ? bsum[t] : 0;
    s[t] = val;
    __syncthreads();
    for (int off = 1; off < PART_BS; off <<= 1) {
        int x = (t >= off) ? s[t - off] : 0;
        __syncthreads();
        s[t] += x;
        __syncthreads();
    }
    if (t < NSCAN_BLOCKS) boff[t] = s[t] - val;   // exclusive
    if (t == 0) row[N_NODES] = N_EDGES;
}

__global__ void final_kernel(const int* __restrict__ cnt,
                             const int* __restrict__ boff,
                             int* __restrict__ row,
                             int* __restrict__ cursor,
                             float* __restrict__ dinv, int n) {
    __shared__ int s[SCAN_BS];
    int t = threadIdx.x;
    int i = blockIdx.x * SCAN_BS + t;
    int val = (i < n) ? cnt[i] : 0;
    s[t] = val;
    __syncthreads();
    for (int off = 1; off < SCAN_BS; off <<= 1) {
        int x = (t >= off) ? s[t - off] : 0;
        __syncthreads();
        s[t] += x;
        __syncthreads();
    }
    if (i < n) {
        int r = boff[blockIdx.x] + s[t] - val;    // exclusive scan
        row[i] = r;
        cursor[i] = r;
        float d = (float)val;
        dinv[i] = rsqrtf(fmaxf(d, 1.0f));
    }
}

__global__ void fill_kernel(const int* __restrict__ edge_src,
                            const int* __restrict__ edge_dst,
                            int* __restrict__ cursor,
                            int* __restrict__ ssrc, int n_edges) {
    int i = blockIdx.x * blockDim.x + threadIdx.x;
    if (i < n_edges) {
        int d = edge_dst[i];
        int pos = atomicAdd(&cursor[d], 1);
        ssrc[pos] = edge_src[i];
    }
}

// one thread per (node, float4-of-features): N_NODES * 8 threads
__global__ void gather_kernel(const float* __restrict__ feat,
                              const int* __restrict__ row,
                              const int* __restrict__ ssrc,
                              const float* __restrict__ dinv,
                              float* __restrict__ out) {
    int gid = blockIdx.x * blockDim.x + threadIdx.x;
    int node = gid >> 3;
    int fq = gid & 7;
    if (node >= N_NODES) return;
    int start = row[node];
    int end = row[node + 1];
    const float4* feat4 = reinterpret_cast<const float4*>(feat);
    float4 acc = make_float4(0.f, 0.f, 0.f, 0.f);
    for (int k = start; k < end; ++k) {
        int s = ssrc[k];
        float dv = dinv[s];
        float4 fv = feat4[s * 8 + fq];
        acc.x += fv.x * dv;
        acc.y += fv.y * dv;
        acc.z += fv.z * dv;
        acc.w += fv.w * dv;
    }
    float dvn = dinv[node];
    float4 fv = feat4[node * 8 + fq];
    float4 o;
    float yx = 0.5f * (fv.x - acc.x * dvn);
    float yy = 0.5f * (fv.y - acc.y * dvn);
    float yz = 0.5f * (fv.z - acc.z * dvn);
    float yw = 0.5f * (fv.w - acc.w * dvn);
    o.x = 2.0f * yx * (fv.x - yx);
    o.y = 2.0f * yy * (fv.y - yy);
    o.z = 2.0f * yz * (fv.z - yz);
    o.w = 2.0f * yw * (fv.w - yw);
    reinterpret_cast<float4*>(out)[gid] = o;
}

extern "C" void kernel_launch(void* const* d_in, const int* in_sizes, int n_in,
                              void* d_out, int out_size, void* d_ws, size_t ws_size,
                              hipStream_t stream) {
    const float* feat = (const float*)d_in[0];
    const int* edge_src = (const int*)d_in[1];
    const int* edge_dst = (const int*)d_in[2];
    float* out = (float*)d_out;

    int* ws = (int*)d_ws;
    int* cnt    = ws;
    int* row    = cnt + N_NODES;
    int* cursor = row + N_NODES + 1;
    int* bsum   = cursor + N_NODES;
    int* boff   = bsum + PART_BS;
    float* dinv = (float*)(boff + PART_BS);
    int* ssrc   = (int*)(dinv + N_NODES);

    // zero only the counts
    hipMemsetAsync(cnt, 0, (size_t)N_NODES * sizeof(int), stream);

    {
        int threads = 256;
        int blocks = (N_EDGES + threads - 1) / threads;
        count_kernel<<<blocks, threads, 0, stream>>>(edge_dst, cnt, N_EDGES);
    }
    reduce_kernel<<<NSCAN_BLOCKS, SCAN_BS, 0, stream>>>(cnt, bsum, N_NODES);
    partials_kernel<<<1, PART_BS, 0, stream>>>(bsum, boff, row);
    final_kernel<<<NSCAN_BLOCKS, SCAN_BS, 0, stream>>>(cnt, boff, row, cursor,
                                                       dinv, N_NODES);
    {
        int threads = 256;
        int blocks = (N_EDGES + threads - 1) / threads;
        fill_kernel<<<blocks, threads, 0, stream>>>(edge_src, edge_dst, cursor,
                                                    ssrc, N_EDGES);
    }
    {
        int threads = 256;
        int total = N_NODES * 8;
        int blocks = (total + threads - 1) / threads;
        gather_kernel<<<blocks, threads, 0, stream>>>(feat, row, ssrc, dinv, out);
    }
}

// Round 3
// 263.789 us; speedup vs baseline: 1.2540x; 1.1924x over previous
//
#include <hip/hip_runtime.h>

#define N_NODES 100000
#define N_EDGES 1600000
#define D_FEAT 32
#define SCAN_BS 1024
#define NSCAN_BLOCKS ((N_NODES + SCAN_BS - 1) / SCAN_BS)   // 98
#define PART_BS 128                                        // >= NSCAN_BLOCKS

#define NBA 25            // coarse buckets: dst >> 12, ceil(100000/4096)
#define P1_BS 512
#define P1_TILE 2048      // 4 edges per thread per tile
#define P1_CAP 256        // staging capacity per bucket

// ws layout (4-byte words):
//   cnt     [N_NODES]      int
//   row     [N_NODES+1]    int    CSR offsets
//   cursor  [N_NODES]      int    per-node fill cursors
//   bsum    [PART_BS]      int
//   boff    [PART_BS]      int
//   cursorA [32]           int    coarse-bucket fill cursors (mutated)
//   baseA   [32]           int    coarse-bucket region starts (pristine)
//   dinv    [N_NODES]      float
//   pairs   [N_EDGES]      int    packed (src<<12)|(dst&4095), bucket-ordered
//   ssrc    [N_EDGES]      int    srcs in final CSR order

__global__ void count_kernel(const int* __restrict__ edge_dst,
                             int* __restrict__ cnt, int n_edges) {
    int i = blockIdx.x * blockDim.x + threadIdx.x;
    if (i < n_edges) atomicAdd(&cnt[edge_dst[i]], 1);
}

__global__ void reduce_kernel(const int* __restrict__ cnt,
                              int* __restrict__ bsum, int n) {
    __shared__ int s[SCAN_BS];
    int t = threadIdx.x;
    int i = blockIdx.x * SCAN_BS + t;
    s[t] = (i < n) ? cnt[i] : 0;
    __syncthreads();
    for (int off = SCAN_BS / 2; off > 0; off >>= 1) {
        if (t < off) s[t] += s[t + off];
        __syncthreads();
    }
    if (t == 0) bsum[blockIdx.x] = s[0];
}

__global__ void partials_kernel(const int* __restrict__ bsum,
                                int* __restrict__ boff,
                                int* __restrict__ row) {
    __shared__ int s[PART_BS];
    int t = threadIdx.x;
    int val = (t < NSCAN_BLOCKS) ? bsum[t] : 0;
    s[t] = val;
    __syncthreads();
    for (int off = 1; off < PART_BS; off <<= 1) {
        int x = (t >= off) ? s[t - off] : 0;
        __syncthreads();
        s[t] += x;
        __syncthreads();
    }
    if (t < NSCAN_BLOCKS) boff[t] = s[t] - val;
    if (t == 0) row[N_NODES] = N_EDGES;
}

__global__ void final_kernel(const int* __restrict__ cnt,
                             const int* __restrict__ boff,
                             int* __restrict__ row,
                             int* __restrict__ cursor,
                             float* __restrict__ dinv, int n) {
    __shared__ int s[SCAN_BS];
    int t = threadIdx.x;
    int i = blockIdx.x * SCAN_BS + t;
    int val = (i < n) ? cnt[i] : 0;
    s[t] = val;
    __syncthreads();
    for (int off = 1; off < SCAN_BS; off <<= 1) {
        int x = (t >= off) ? s[t - off] : 0;
        __syncthreads();
        s[t] += x;
        __syncthreads();
    }
    if (i < n) {
        int r = boff[blockIdx.x] + s[t] - val;
        row[i] = r;
        cursor[i] = r;
        dinv[i] = rsqrtf(fmaxf((float)val, 1.0f));
    }
}

__global__ void initA_kernel(const int* __restrict__ row,
                             int* __restrict__ cursorA,
                             int* __restrict__ baseA) {
    int b = threadIdx.x;
    if (b < NBA) {
        int r = row[b << 12];
        cursorA[b] = r;
        baseA[b] = r;
    }
    if (b == NBA) baseA[NBA] = N_EDGES;
}

// Pass 1: bucket edges by dst>>12 with LDS staging -> coalesced runs
__global__ void __launch_bounds__(P1_BS)
bucket_kernel(const int* __restrict__ edge_src,
              const int* __restrict__ edge_dst,
              int* __restrict__ cursorA,
              int* __restrict__ pairs, int n_edges) {
    __shared__ int s_cnt[NBA];
    __shared__ int s_base[NBA];
    __shared__ int s_off[NBA + 1];
    __shared__ int s_buf[NBA * P1_CAP];   // 25*256*4 = 25.6 KB

    int tile = blockIdx.x * P1_TILE;
    if (tile >= n_edges) return;

    for (int b = threadIdx.x; b < NBA; b += P1_BS) s_cnt[b] = 0;
    __syncthreads();

    #pragma unroll
    for (int j = 0; j < 4; ++j) {
        int i = tile + j * P1_BS + threadIdx.x;
        if (i < n_edges) {
            int src = edge_src[i];
            int dst = edge_dst[i];
            int b = dst >> 12;
            int packed = (src << 12) | (dst & 4095);
            int p = atomicAdd(&s_cnt[b], 1);
            if (p < P1_CAP) {
                s_buf[b * P1_CAP + p] = packed;
            } else {
                int gp = atomicAdd(&cursorA[b], 1);   // rare overflow path
                pairs[gp] = packed;
            }
        }
    }
    __syncthreads();

    if (threadIdx.x < NBA) {
        int c = min(s_cnt[threadIdx.x], P1_CAP);
        s_base[threadIdx.x] = atomicAdd(&cursorA[threadIdx.x], c);
        s_cnt[threadIdx.x] = c;
    }
    __syncthreads();
    if (threadIdx.x == 0) {
        int acc = 0;
        for (int b = 0; b < NBA; ++b) { s_off[b] = acc; acc += s_cnt[b]; }
        s_off[NBA] = acc;
    }
    __syncthreads();

    int total = s_off[NBA];
    for (int t = threadIdx.x; t < total; t += P1_BS) {
        int lo = 0, hi = NBA;
        while (hi - lo > 1) {
            int mid = (lo + hi) >> 1;
            if (t >= s_off[mid]) lo = mid; else hi = mid;
        }
        int idx = t - s_off[lo];
        pairs[s_base[lo] + idx] = s_buf[lo * P1_CAP + idx];
    }
}

// Pass 2: scatter within coarse-bucket regions (L2-local writes)
__global__ void fill2_kernel(const int* __restrict__ pairs,
                             const int* __restrict__ baseA,
                             int* __restrict__ cursor,
                             int* __restrict__ ssrc, int n_edges) {
    __shared__ int sA[NBA + 1];
    if (threadIdx.x <= NBA) sA[threadIdx.x] = baseA[threadIdx.x];
    __syncthreads();
    int i = blockIdx.x * blockDim.x + threadIdx.x;
    if (i >= n_edges) return;
    int p = pairs[i];
    // find bucket b: sA[b] <= i < sA[b+1]
    int lo = 0, hi = NBA;
    while (hi - lo > 1) {
        int mid = (lo + hi) >> 1;
        if (i >= sA[mid]) lo = mid; else hi = mid;
    }
    int dst = (lo << 12) | (p & 4095);
    int src = p >> 12;
    int pos = atomicAdd(&cursor[dst], 1);
    ssrc[pos] = src;
}

// one thread per (node, float4): N_NODES*8 threads, 4x unrolled edge loop
__global__ void gather_kernel(const float* __restrict__ feat,
                              const int* __restrict__ row,
                              const int* __restrict__ ssrc,
                              const float* __restrict__ dinv,
                              float* __restrict__ out) {
    int gid = blockIdx.x * blockDim.x + threadIdx.x;
    int node = gid >> 3;
    int fq = gid & 7;
    if (node >= N_NODES) return;
    int start = row[node];
    int end = row[node + 1];
    const float4* feat4 = reinterpret_cast<const float4*>(feat);
    float4 acc = make_float4(0.f, 0.f, 0.f, 0.f);
    int k = start;
    for (; k + 3 < end; k += 4) {
        int s0 = ssrc[k],     s1 = ssrc[k + 1];
        int s2 = ssrc[k + 2], s3 = ssrc[k + 3];
        float4 f0 = feat4[s0 * 8 + fq];
        float4 f1 = feat4[s1 * 8 + fq];
        float4 f2 = feat4[s2 * 8 + fq];
        float4 f3 = feat4[s3 * 8 + fq];
        float d0 = dinv[s0], d1 = dinv[s1], d2 = dinv[s2], d3 = dinv[s3];
        acc.x += f0.x * d0 + f1.x * d1 + f2.x * d2 + f3.x * d3;
        acc.y += f0.y * d0 + f1.y * d1 + f2.y * d2 + f3.y * d3;
        acc.z += f0.z * d0 + f1.z * d1 + f2.z * d2 + f3.z * d3;
        acc.w += f0.w * d0 + f1.w * d1 + f2.w * d2 + f3.w * d3;
    }
    for (; k < end; ++k) {
        int s = ssrc[k];
        float dv = dinv[s];
        float4 fv = feat4[s * 8 + fq];
        acc.x += fv.x * dv;
        acc.y += fv.y * dv;
        acc.z += fv.z * dv;
        acc.w += fv.w * dv;
    }
    float dvn = dinv[node];
    float4 fv = feat4[node * 8 + fq];
    float4 o;
    float yx = 0.5f * (fv.x - acc.x * dvn);
    float yy = 0.5f * (fv.y - acc.y * dvn);
    float yz = 0.5f * (fv.z - acc.z * dvn);
    float yw = 0.5f * (fv.w - acc.w * dvn);
    o.x = 2.0f * yx * (fv.x - yx);
    o.y = 2.0f * yy * (fv.y - yy);
    o.z = 2.0f * yz * (fv.z - yz);
    o.w = 2.0f * yw * (fv.w - yw);
    reinterpret_cast<float4*>(out)[gid] = o;
}

extern "C" void kernel_launch(void* const* d_in, const int* in_sizes, int n_in,
                              void* d_out, int out_size, void* d_ws, size_t ws_size,
                              hipStream_t stream) {
    const float* feat = (const float*)d_in[0];
    const int* edge_src = (const int*)d_in[1];
    const int* edge_dst = (const int*)d_in[2];
    float* out = (float*)d_out;

    int* ws = (int*)d_ws;
    int* cnt     = ws;
    int* row     = cnt + N_NODES;
    int* cursor  = row + N_NODES + 1;
    int* bsum    = cursor + N_NODES;
    int* boff    = bsum + PART_BS;
    int* cursorA = boff + PART_BS;
    int* baseA   = cursorA + 32;
    float* dinv  = (float*)(baseA + 32);
    int* pairs   = (int*)(dinv + N_NODES);
    int* ssrc    = pairs + N_EDGES;

    hipMemsetAsync(cnt, 0, (size_t)N_NODES * sizeof(int), stream);

    {
        int threads = 256;
        int blocks = (N_EDGES + threads - 1) / threads;
        count_kernel<<<blocks, threads, 0, stream>>>(edge_dst, cnt, N_EDGES);
    }
    reduce_kernel<<<NSCAN_BLOCKS, SCAN_BS, 0, stream>>>(cnt, bsum, N_NODES);
    partials_kernel<<<1, PART_BS, 0, stream>>>(bsum, boff, row);
    final_kernel<<<NSCAN_BLOCKS, SCAN_BS, 0, stream>>>(cnt, boff, row, cursor,
                                                       dinv, N_NODES);
    initA_kernel<<<1, 64, 0, stream>>>(row, cursorA, baseA);
    {
        int blocks = (N_EDGES + P1_TILE - 1) / P1_TILE;   // 782
        bucket_kernel<<<blocks, P1_BS, 0, stream>>>(edge_src, edge_dst,
                                                    cursorA, pairs, N_EDGES);
    }
    {
        int threads = 256;
        int blocks = (N_EDGES + threads - 1) / threads;
        fill2_kernel<<<blocks, threads, 0, stream>>>(pairs, baseA, cursor,
                                                     ssrc, N_EDGES);
    }
    {
        int threads = 256;
        int total = N_NODES * 8;
        int blocks = (total + threads - 1) / threads;
        gather_kernel<<<blocks, threads, 0, stream>>>(feat, row, ssrc, dinv, out);
    }
}

// Round 4
// 263.724 us; speedup vs baseline: 1.2543x; 1.0002x over previous
//
#include <hip/hip_runtime.h>

#define N_NODES 100000
#define N_EDGES 1600000
#define D_FEAT 32
#define SCAN_BS 1024
#define NSCAN_BLOCKS ((N_NODES + SCAN_BS - 1) / SCAN_BS)   // 98
#define PART_BS 128                                        // >= NSCAN_BLOCKS

#define NBA 25            // coarse buckets: dst >> 12, ceil(100000/4096)
#define P1_BS 512
#define P1_TILE 2048      // 4 edges per thread per tile
#define P1_CAP 256        // staging capacity per bucket

#define FILL2_SLOTS 128   // blocks per XCD group; grid = 8 * FILL2_SLOTS

// ws layout (4-byte words):
//   cnt     [N_NODES]      int
//   row     [N_NODES+1]    int    CSR offsets
//   cursor  [N_NODES]      int    per-node fill cursors
//   bsum    [PART_BS]      int
//   boff    [PART_BS]      int
//   cursorA [32]           int    coarse-bucket fill cursors (mutated)
//   baseA   [32]           int    coarse-bucket region starts (pristine)
//   dinv    [N_NODES]      float
//   pairs   [N_EDGES]      int    packed (src<<12)|(dst&4095), bucket-ordered
//   ssrc    [N_EDGES]      int    srcs in final CSR order

__global__ void count_kernel(const int* __restrict__ edge_dst,
                             int* __restrict__ cnt, int n_edges) {
    int i = blockIdx.x * blockDim.x + threadIdx.x;
    if (i < n_edges) atomicAdd(&cnt[edge_dst[i]], 1);
}

__global__ void reduce_kernel(const int* __restrict__ cnt,
                              int* __restrict__ bsum, int n) {
    __shared__ int s[SCAN_BS];
    int t = threadIdx.x;
    int i = blockIdx.x * SCAN_BS + t;
    s[t] = (i < n) ? cnt[i] : 0;
    __syncthreads();
    for (int off = SCAN_BS / 2; off > 0; off >>= 1) {
        if (t < off) s[t] += s[t + off];
        __syncthreads();
    }
    if (t == 0) bsum[blockIdx.x] = s[0];
}

__global__ void partials_kernel(const int* __restrict__ bsum,
                                int* __restrict__ boff,
                                int* __restrict__ row) {
    __shared__ int s[PART_BS];
    int t = threadIdx.x;
    int val = (t < NSCAN_BLOCKS) ? bsum[t] : 0;
    s[t] = val;
    __syncthreads();
    for (int off = 1; off < PART_BS; off <<= 1) {
        int x = (t >= off) ? s[t - off] : 0;
        __syncthreads();
        s[t] += x;
        __syncthreads();
    }
    if (t < NSCAN_BLOCKS) boff[t] = s[t] - val;
    if (t == 0) row[N_NODES] = N_EDGES;
}

__global__ void final_kernel(const int* __restrict__ cnt,
                             const int* __restrict__ boff,
                             int* __restrict__ row,
                             int* __restrict__ cursor,
                             float* __restrict__ dinv, int n) {
    __shared__ int s[SCAN_BS];
    int t = threadIdx.x;
    int i = blockIdx.x * SCAN_BS + t;
    int val = (i < n) ? cnt[i] : 0;
    s[t] = val;
    __syncthreads();
    for (int off = 1; off < SCAN_BS; off <<= 1) {
        int x = (t >= off) ? s[t - off] : 0;
        __syncthreads();
        s[t] += x;
        __syncthreads();
    }
    if (i < n) {
        int r = boff[blockIdx.x] + s[t] - val;
        row[i] = r;
        cursor[i] = r;
        dinv[i] = rsqrtf(fmaxf((float)val, 1.0f));
    }
}

__global__ void initA_kernel(const int* __restrict__ row,
                             int* __restrict__ cursorA,
                             int* __restrict__ baseA) {
    int b = threadIdx.x;
    if (b < NBA) {
        int r = row[b << 12];
        cursorA[b] = r;
        baseA[b] = r;
    }
    if (b == NBA) baseA[NBA] = N_EDGES;
}

// Pass 1: bucket edges by dst>>12 with LDS staging -> coalesced runs
__global__ void __launch_bounds__(P1_BS)
bucket_kernel(const int* __restrict__ edge_src,
              const int* __restrict__ edge_dst,
              int* __restrict__ cursorA,
              int* __restrict__ pairs, int n_edges) {
    __shared__ int s_cnt[NBA];
    __shared__ int s_base[NBA];
    __shared__ int s_off[NBA + 1];
    __shared__ int s_buf[NBA * P1_CAP];   // 25*256*4 = 25.6 KB

    int tile = blockIdx.x * P1_TILE;
    if (tile >= n_edges) return;

    for (int b = threadIdx.x; b < NBA; b += P1_BS) s_cnt[b] = 0;
    __syncthreads();

    #pragma unroll
    for (int j = 0; j < 4; ++j) {
        int i = tile + j * P1_BS + threadIdx.x;
        if (i < n_edges) {
            int src = edge_src[i];
            int dst = edge_dst[i];
            int b = dst >> 12;
            int packed = (src << 12) | (dst & 4095);
            int p = atomicAdd(&s_cnt[b], 1);
            if (p < P1_CAP) {
                s_buf[b * P1_CAP + p] = packed;
            } else {
                int gp = atomicAdd(&cursorA[b], 1);   // rare overflow path
                pairs[gp] = packed;
            }
        }
    }
    __syncthreads();

    if (threadIdx.x < NBA) {
        int c = min(s_cnt[threadIdx.x], P1_CAP);
        s_base[threadIdx.x] = atomicAdd(&cursorA[threadIdx.x], c);
        s_cnt[threadIdx.x] = c;
    }
    __syncthreads();
    if (threadIdx.x == 0) {
        int acc = 0;
        for (int b = 0; b < NBA; ++b) { s_off[b] = acc; acc += s_cnt[b]; }
        s_off[NBA] = acc;
    }
    __syncthreads();

    int total = s_off[NBA];
    for (int t = threadIdx.x; t < total; t += P1_BS) {
        int lo = 0, hi = NBA;
        while (hi - lo > 1) {
            int mid = (lo + hi) >> 1;
            if (t >= s_off[mid]) lo = mid; else hi = mid;
        }
        int idx = t - s_off[lo];
        pairs[s_base[lo] + idx] = s_buf[lo * P1_CAP + idx];
    }
}

// Pass 2: scatter within coarse-bucket regions, XCD-affine:
// bucket b handled only by blocks with blockIdx%8 == b%8, so all writes to
// one bucket's ssrc region come from a single XCD's L2.
__global__ void fill2_kernel(const int* __restrict__ pairs,
                             const int* __restrict__ baseA,
                             int* __restrict__ cursor,
                             int* __restrict__ ssrc) {
    __shared__ int sA[NBA + 1];
    if (threadIdx.x <= NBA) sA[threadIdx.x] = baseA[threadIdx.x];
    __syncthreads();
    int x = blockIdx.x & 7;
    int slot = blockIdx.x >> 3;
    for (int b = x; b < NBA; b += 8) {
        int lo = sA[b], hi = sA[b + 1];
        int len = hi - lo;
        int chunk = (len + FILL2_SLOTS - 1) / FILL2_SLOTS;
        int s0 = lo + slot * chunk;
        int s1 = min(s0 + chunk, hi);
        for (int i = s0 + (int)threadIdx.x; i < s1; i += (int)blockDim.x) {
            int p = pairs[i];
            int dst = (b << 12) | (p & 4095);
            int src = p >> 12;
            int pos = atomicAdd(&cursor[dst], 1);
            ssrc[pos] = src;
        }
    }
}

// one thread per (node, float4): N_NODES*8 threads, 4x unrolled edge loop
__global__ void gather_kernel(const float* __restrict__ feat,
                              const int* __restrict__ row,
                              const int* __restrict__ ssrc,
                              const float* __restrict__ dinv,
                              float* __restrict__ out) {
    int gid = blockIdx.x * blockDim.x + threadIdx.x;
    int node = gid >> 3;
    int fq = gid & 7;
    if (node >= N_NODES) return;
    int start = row[node];
    int end = row[node + 1];
    const float4* feat4 = reinterpret_cast<const float4*>(feat);
    float4 acc = make_float4(0.f, 0.f, 0.f, 0.f);
    int k = start;
    for (; k + 3 < end; k += 4) {
        int s0 = ssrc[k],     s1 = ssrc[k + 1];
        int s2 = ssrc[k + 2], s3 = ssrc[k + 3];
        float4 f0 = feat4[s0 * 8 + fq];
        float4 f1 = feat4[s1 * 8 + fq];
        float4 f2 = feat4[s2 * 8 + fq];
        float4 f3 = feat4[s3 * 8 + fq];
        float d0 = dinv[s0], d1 = dinv[s1], d2 = dinv[s2], d3 = dinv[s3];
        acc.x += f0.x * d0 + f1.x * d1 + f2.x * d2 + f3.x * d3;
        acc.y += f0.y * d0 + f1.y * d1 + f2.y * d2 + f3.y * d3;
        acc.z += f0.z * d0 + f1.z * d1 + f2.z * d2 + f3.z * d3;
        acc.w += f0.w * d0 + f1.w * d1 + f2.w * d2 + f3.w * d3;
    }
    for (; k < end; ++k) {
        int s = ssrc[k];
        float dv = dinv[s];
        float4 fv = feat4[s * 8 + fq];
        acc.x += fv.x * dv;
        acc.y += fv.y * dv;
        acc.z += fv.z * dv;
        acc.w += fv.w * dv;
    }
    float dvn = dinv[node];
    float4 fv = feat4[node * 8 + fq];
    float4 o;
    float yx = 0.5f * (fv.x - acc.x * dvn);
    float yy = 0.5f * (fv.y - acc.y * dvn);
    float yz = 0.5f * (fv.z - acc.z * dvn);
    float yw = 0.5f * (fv.w - acc.w * dvn);
    o.x = 2.0f * yx * (fv.x - yx);
    o.y = 2.0f * yy * (fv.y - yy);
    o.z = 2.0f * yz * (fv.z - yz);
    o.w = 2.0f * yw * (fv.w - yw);
    reinterpret_cast<float4*>(out)[gid] = o;
}

extern "C" void kernel_launch(void* const* d_in, const int* in_sizes, int n_in,
                              void* d_out, int out_size, void* d_ws, size_t ws_size,
                              hipStream_t stream) {
    const float* feat = (const float*)d_in[0];
    const int* edge_src = (const int*)d_in[1];
    const int* edge_dst = (const int*)d_in[2];
    float* out = (float*)d_out;

    int* ws = (int*)d_ws;
    int* cnt     = ws;
    int* row     = cnt + N_NODES;
    int* cursor  = row + N_NODES + 1;
    int* bsum    = cursor + N_NODES;
    int* boff    = bsum + PART_BS;
    int* cursorA = boff + PART_BS;
    int* baseA   = cursorA + 32;
    float* dinv  = (float*)(baseA + 32);
    int* pairs   = (int*)(dinv + N_NODES);
    int* ssrc    = pairs + N_EDGES;

    hipMemsetAsync(cnt, 0, (size_t)N_NODES * sizeof(int), stream);

    {
        int threads = 256;
        int blocks = (N_EDGES + threads - 1) / threads;
        count_kernel<<<blocks, threads, 0, stream>>>(edge_dst, cnt, N_EDGES);
    }
    reduce_kernel<<<NSCAN_BLOCKS, SCAN_BS, 0, stream>>>(cnt, bsum, N_NODES);
    partials_kernel<<<1, PART_BS, 0, stream>>>(bsum, boff, row);
    final_kernel<<<NSCAN_BLOCKS, SCAN_BS, 0, stream>>>(cnt, boff, row, cursor,
                                                       dinv, N_NODES);
    initA_kernel<<<1, 64, 0, stream>>>(row, cursorA, baseA);
    {
        int blocks = (N_EDGES + P1_TILE - 1) / P1_TILE;   // 782
        bucket_kernel<<<blocks, P1_BS, 0, stream>>>(edge_src, edge_dst,
                                                    cursorA, pairs, N_EDGES);
    }
    {
        fill2_kernel<<<8 * FILL2_SLOTS, 256, 0, stream>>>(pairs, baseA,
                                                          cursor, ssrc);
    }
    {
        int threads = 256;
        int total = N_NODES * 8;
        int blocks = (total + threads - 1) / threads;
        gather_kernel<<<blocks, threads, 0, stream>>>(feat, row, ssrc, dinv, out);
    }
}